// Round 14
// baseline (74.587 us; speedup 1.0000x reference)
//
#include <hip/hip_runtime.h>

#define EDGE 4096
#define NPIX (EDGE * EDGE)
#define TILES_X 64
#define NTILES (TILES_X * TILES_X)   // 4096 tiles of 64x64
#define SLOTS 2048                   // max runs in a 64x64 tile (32/row x 64)

typedef unsigned long long u64;

// ================= global forest (compact rank space, halving) =============
static __device__ __forceinline__ int g_load(int* L, int i) {
    return __hip_atomic_load(&L[i], __ATOMIC_RELAXED, __HIP_MEMORY_SCOPE_AGENT);
}
static __device__ __forceinline__ void g_store(int* L, int i, int v) {
    __hip_atomic_store(&L[i], v, __ATOMIC_RELAXED, __HIP_MEMORY_SCOPE_AGENT);
}
static __device__ int g_find(int* L, int i) {
    while (true) {
        const int p = g_load(L, i);
        if (p == i) return i;
        const int gp = g_load(L, p);
        if (gp == p) return p;
        g_store(L, i, gp);          // halve: gp < p < i, ancestor of i
        i = gp;
    }
}
static __device__ int g_unite(int* L, int a, int b) {   // returns captures (0/1)
    while (true) {
        a = g_find(L, a); b = g_find(L, b);
        if (a == b) return 0;
        const int lo = a < b ? a : b;
        const int hi = a ^ b ^ lo;
        const int old = atomicMin(&L[hi], lo);
        if (old == hi) return 1;    // hi was root: one set merged away
        a = lo; b = old;            // displaced value must be re-merged
    }
}

// ================= LDS union-find (pointer-halving) =================
static __device__ __forceinline__ int l_load(int* L, int i) {
    return __hip_atomic_load(&L[i], __ATOMIC_RELAXED, __HIP_MEMORY_SCOPE_WORKGROUP);
}
static __device__ __forceinline__ void l_store(int* L, int i, int v) {
    __hip_atomic_store(&L[i], v, __ATOMIC_RELAXED, __HIP_MEMORY_SCOPE_WORKGROUP);
}
static __device__ int l_find(int* L, int i) {
    while (true) {
        const int p = l_load(L, i);
        if (p == i) return i;
        const int gp = l_load(L, p);
        if (gp == p) return p;
        l_store(L, i, gp);
        i = gp;
    }
}
static __device__ void l_unite(int* L, int a, int b) {
    while (true) {
        a = l_find(L, a); b = l_find(L, b);
        if (a == b) return;
        const int lo = a < b ? a : b;
        const int hi = a ^ b ^ lo;
        const int old = atomicMin(&L[hi], lo);
        if (old == hi) return;
        a = lo; b = old;
    }
}

// ======= fused pass A+B: mask + tanh + run-based tile CCL (R11 exact) ======
__global__ __launch_bounds__(256) void k_tile(const float* __restrict__ x,
                                              int* __restrict__ G,
                                              int* __restrict__ topM, int* __restrict__ botM,
                                              int* __restrict__ leftM, int* __restrict__ rightM,
                                              int* __restrict__ rootsArr,
                                              double* __restrict__ partials) {
    __shared__ u64 mrow[64];
    __shared__ u64 rstart[64];
    __shared__ unsigned int mpart[64][4];
    __shared__ int rowbase[64];
    __shared__ int P[SLOTS];
    __shared__ int wtot[4];
    __shared__ double wsum[4];
    __shared__ int Rtot;
    const int t = threadIdx.x;
    const int tile = blockIdx.x;
    const int tr = tile >> 6, tc = tile & 63;

    // --- ph1: load own 16 pixels (row r, quarter qd): mask + tanh sum ---
    const int r = t >> 2, qd = t & 3;
    const float4* xp = reinterpret_cast<const float4*>(
        x + ((size_t)((tr << 6) | r) << 12) + (tc << 6) + (qd << 4));
    unsigned int m16 = 0;
    float sf = 0.0f;
    #pragma unroll
    for (int k = 0; k < 4; ++k) {
        const float4 a = xp[k];
        const float vv[4] = {a.x, a.y, a.z, a.w};
        #pragma unroll
        for (int j = 0; j < 4; ++j) {
            const float v = vv[j];
            if (v > 0.0f) {                        // tanh(x)>0 <=> x>0
                m16 |= 1u << (k * 4 + j);
                const float e = __expf(2.0f * v);  // tanh = 1 - 2/(e^{2x}+1)
                sf += 1.0f - 2.0f * __builtin_amdgcn_rcpf(e + 1.0f);
            }
        }
    }
    mpart[r][qd] = m16;
    double s = (double)sf;
    for (int off = 32; off > 0; off >>= 1) s += __shfl_down(s, off, 64);
    if ((t & 63) == 0) wsum[t >> 6] = s;
    __syncthreads();                                             // b1

    // --- ph2: wave0 row masks + run scan; all: P init ---
    if (t < 64) {
        const u64 m = (u64)mpart[t][0] | ((u64)mpart[t][1] << 16)
                    | ((u64)mpart[t][2] << 32) | ((u64)mpart[t][3] << 48);
        mrow[t] = m;
        const u64 rs = m & ~(m << 1);
        rstart[t] = rs;
        int inc = __popcll(rs);
        const int nr = inc;
        #pragma unroll
        for (int off = 1; off < 64; off <<= 1) {
            const int v = __shfl_up(inc, off, 64);
            if (t >= off) inc += v;
        }
        rowbase[t] = inc - nr;
        if (t == 63) Rtot = inc;
    }
    #pragma unroll
    for (int i = t; i < SLOTS; i += 256) P[i] = i;
    if (t == 0) partials[tile] = wsum[0] + wsum[1] + wsum[2] + wsum[3];
    __syncthreads();                                             // b2

    // --- ph3: unions, one per overlap segment (hook fast-path) ---
    {
        const int rr = t >> 2;
        if (rr >= 1) {
            const u64 vm = mrow[rr] & mrow[rr - 1];
            u64 st = vm & ~(vm << 1);
            const int cb = (t & 3) * 16;
            st = (st >> cb) & 0xFFFFull;
            if (st) {
                const u64 rs  = rstart[rr];
                const u64 rsu = rstart[rr - 1];
                const int rb  = rowbase[rr];
                const int rbu = rowbase[rr - 1];
                do {
                    const int j = __builtin_ctzll(st) + cb;
                    const u64 thru = ~0ull >> (63 - j);
                    const int na = rb  + __popcll(rs  & thru) - 1;
                    const int nb = rbu + __popcll(rsu & thru) - 1;
                    const int old = atomicMin(&P[na], nb);
                    if (old != na && old != nb) l_unite(P, nb, old);
                    st &= st - 1;
                } while (st);
            }
        }
    }
    __syncthreads();                                             // b3

    // --- ph4: border finds + root count + wave scan ---
    const int R = Rtot;
    int broot = -1;
    {
        int rr, j;
        if (t < 64)       { rr = 0;       j = t; }
        else if (t < 128) { rr = 63;      j = t - 64; }
        else if (t < 192) { rr = t - 128; j = 0; }
        else              { rr = t - 192; j = 63; }
        if ((mrow[rr] >> j) & 1ull) {
            const int idx = __popcll(rstart[rr] & (~0ull >> (63 - j))) - 1;
            broot = l_find(P, rowbase[rr] + idx);
        }
    }
    int c = 0;
    for (int i = t; i < R; i += 256) c += (P[i] == i);
    int inc2 = c;
    #pragma unroll
    for (int off = 1; off < 64; off <<= 1) {
        const int v = __shfl_up(inc2, off, 64);
        if ((t & 63) >= off) inc2 += v;
    }
    if ((t & 63) == 63) wtot[t >> 6] = inc2;
    __syncthreads();                                             // b4

    // --- ph5: remap roots -> compact ranks; init G root slots ---
    const int w = t >> 6;
    int wbase = 0;
    if (w > 0) wbase += wtot[0];
    if (w > 1) wbase += wtot[1];
    if (w > 2) wbase += wtot[2];
    const int my_base = wbase + inc2 - c;
    const int nroots = wtot[0] + wtot[1] + wtot[2] + wtot[3];
    const int tileBase = tile * SLOTS;
    {
        int k = my_base;
        for (int i = t; i < R; i += 256) if (P[i] == i) P[i] = k++;
    }
    for (int i = t; i < nroots; i += 256) G[tileBase + i] = tileBase + i;
    __syncthreads();                                             // b5

    // --- ph6: publish border node IDs (-1 = unmasked) ---
    {
        const int node = (broot >= 0) ? (tileBase + P[broot]) : -1;
        const int bi = (tile << 6) | (t & 63);
        if (t < 64)       topM[bi]   = node;
        else if (t < 128) botM[bi]   = node;
        else if (t < 192) leftM[bi]  = node;
        else              rightM[bi] = node;
    }
    if (t == 0) rootsArr[tile] = nroots;
}

// ===== ABLATION dispatch: phase 1+2 ONLY (results kept live in scratch) =====
__global__ __launch_bounds__(256) void k_ph1(const float* __restrict__ x,
                                             u64* __restrict__ mrowDump,
                                             double* __restrict__ partials2) {
    __shared__ unsigned int mpart[64][4];
    __shared__ double wsum[4];
    const int t = threadIdx.x;
    const int tile = blockIdx.x;
    const int tr = tile >> 6, tc = tile & 63;

    const int r = t >> 2, qd = t & 3;
    const float4* xp = reinterpret_cast<const float4*>(
        x + ((size_t)((tr << 6) | r) << 12) + (tc << 6) + (qd << 4));
    unsigned int m16 = 0;
    float sf = 0.0f;
    #pragma unroll
    for (int k = 0; k < 4; ++k) {
        const float4 a = xp[k];
        const float vv[4] = {a.x, a.y, a.z, a.w};
        #pragma unroll
        for (int j = 0; j < 4; ++j) {
            const float v = vv[j];
            if (v > 0.0f) {
                m16 |= 1u << (k * 4 + j);
                const float e = __expf(2.0f * v);
                sf += 1.0f - 2.0f * __builtin_amdgcn_rcpf(e + 1.0f);
            }
        }
    }
    mpart[r][qd] = m16;
    double s = (double)sf;
    for (int off = 32; off > 0; off >>= 1) s += __shfl_down(s, off, 64);
    if ((t & 63) == 0) wsum[t >> 6] = s;
    __syncthreads();
    if (t < 64) {
        const u64 m = (u64)mpart[t][0] | ((u64)mpart[t][1] << 16)
                    | ((u64)mpart[t][2] << 32) | ((u64)mpart[t][3] << 48);
        mrowDump[(tile << 6) | t] = m;       // keep live, coalesced
    }
    if (t == 0) partials2[tile] = wsum[0] + wsum[1] + wsum[2] + wsum[3];
}

// ================= pass C: cross-tile unions (R11 exact) =========
__global__ __launch_bounds__(128) void k_xmerge(const int* __restrict__ topM,
                                                const int* __restrict__ botM,
                                                const int* __restrict__ leftM,
                                                const int* __restrict__ rightM,
                                                int* G, int* __restrict__ linksArr) {
    __shared__ int lsum[2];
    const int t = threadIdx.x, tile = blockIdx.x;
    const int tr = tile >> 6, tc = tile & 63;
    int links = 0;
    if (t < 64) {
        if (tr > 0) {
            const int a = topM[(tile << 6) | t];
            const int b = botM[((tile - 64) << 6) | t];
            const int ap = __shfl_up(a, 1, 64);
            const int bp = __shfl_up(b, 1, 64);
            if ((a | b) >= 0) {
                const bool redund = (t > 0) && ((ap | bp) >= 0);
                if (!redund) links = g_unite(G, a, b);
            }
        }
    } else {
        const int rr = t - 64;
        if (tc > 0) {
            const int a = leftM[(tile << 6) | rr];
            const int b = rightM[((tile - 1) << 6) | rr];
            const int ap = __shfl_up(a, 1, 64);
            const int bp = __shfl_up(b, 1, 64);
            if ((a | b) >= 0) {
                const bool redund = (rr > 0) && ((ap | bp) >= 0);
                if (!redund) links = g_unite(G, a, b);
            }
        }
    }
    for (int off = 32; off > 0; off >>= 1) links += __shfl_down(links, off, 64);
    if ((t & 63) == 0) lsum[t >> 6] = links;
    __syncthreads();
    if (t == 0) linksArr[tile] = lsum[0] + lsum[1];
}

// ================= pass D: tiny final reduction =================
__global__ __launch_bounds__(256) void k_final(const double* __restrict__ partials,
                                               const int* __restrict__ rootsArr,
                                               const int* __restrict__ linksArr,
                                               float* __restrict__ out) {
    __shared__ double sd[256];
    __shared__ int si[256];
    const int t = threadIdx.x;
    double s = 0.0; int n = 0;
    for (int i = t; i < NTILES; i += 256) {
        s += partials[i];
        n += rootsArr[i] - linksArr[i];
    }
    sd[t] = s; si[t] = n; __syncthreads();
    for (int off = 128; off > 0; off >>= 1) {
        if (t < off) { sd[t] += sd[t + off]; si[t] += si[t + off]; }
        __syncthreads();
    }
    if (t == 0) {
        const int nn = si[0];
        out[0] = (nn > 0) ? (float)(sd[0] / (double)(NPIX + 1) / (double)nn) : 0.0f;
    }
}

// ================= launch =================
extern "C" void kernel_launch(void* const* d_in, const int* in_sizes, int n_in,
                              void* d_out, int out_size, void* d_ws, size_t ws_size,
                              hipStream_t stream) {
    const float* x = (const float*)d_in[0];
    float* out = (float*)d_out;

    char* ws = (char*)d_ws;
    int* G = (int*)ws;                                         // 32 MB
    int* topM   = (int*)(ws + (32u << 20));                    // 1 MB each
    int* botM   = topM  + NTILES * 64;
    int* leftM  = botM  + NTILES * 64;
    int* rightM = leftM + NTILES * 64;
    double* partials = (double*)(ws + (36u << 20));            // 32 KB
    int* rootsArr = (int*)(ws + (36u << 20) + (64u << 10));    // 16 KB
    int* linksArr = (int*)(ws + (36u << 20) + (80u << 10));    // 16 KB
    u64* mrowDump = (u64*)(ws + (40u << 20));                  // 2 MB (ablation)
    double* partials2 = (double*)(ws + (43u << 20));           // 32 KB (ablation)

    k_tile  <<<NTILES, 256, 0, stream>>>(x, G, topM, botM, leftM, rightM,
                                         rootsArr, partials);
    k_xmerge<<<NTILES, 128, 0, stream>>>(topM, botM, leftM, rightM, G, linksArr);
    k_final <<<1, 256, 0, stream>>>(partials, rootsArr, linksArr, out);
    // ---- ablation: phase-1-only timing probe (output unused) ----
    k_ph1   <<<NTILES, 256, 0, stream>>>(x, mrowDump, partials2);
}

// Round 15
// 55.977 us; speedup vs baseline: 1.3325x; 1.3325x over previous
//
#include <hip/hip_runtime.h>

#define EDGE 4096
#define NPIX (EDGE * EDGE)
#define TILES_X 64
#define NTILES (TILES_X * TILES_X)   // 4096 tiles of 64x64
#define SLOTS 2048                   // max runs in a 64x64 tile (32/row x 64)

typedef unsigned long long u64;

// ================= global forest (run-root space, pointer-halving) ==========
// Invariant: L[n] <= n and only decreases (atomicMin; halving stores write
// ancestors < n). Root = min of tree -> every atomicMin capture (old==hi)
// merges two DISTINCT sets. n_comp = n_roots - n_captures, exactly.
static __device__ __forceinline__ int g_load(int* L, int i) {
    return __hip_atomic_load(&L[i], __ATOMIC_RELAXED, __HIP_MEMORY_SCOPE_AGENT);
}
static __device__ __forceinline__ void g_store(int* L, int i, int v) {
    __hip_atomic_store(&L[i], v, __ATOMIC_RELAXED, __HIP_MEMORY_SCOPE_AGENT);
}
static __device__ int g_find(int* L, int i) {
    while (true) {
        const int p = g_load(L, i);
        if (p == i) return i;
        const int gp = g_load(L, p);
        if (gp == p) return p;
        g_store(L, i, gp);          // halve: gp < p < i, ancestor of i
        i = gp;
    }
}
static __device__ int g_unite(int* L, int a, int b) {   // returns captures (0/1)
    while (true) {
        a = g_find(L, a); b = g_find(L, b);
        if (a == b) return 0;
        const int lo = a < b ? a : b;
        const int hi = a ^ b ^ lo;
        const int old = atomicMin(&L[hi], lo);
        if (old == hi) return 1;    // hi was root: one set merged away
        a = lo; b = old;            // displaced value must be re-merged
    }
}

// ================= LDS union-find (pointer-halving) =================
static __device__ __forceinline__ int l_load(int* L, int i) {
    return __hip_atomic_load(&L[i], __ATOMIC_RELAXED, __HIP_MEMORY_SCOPE_WORKGROUP);
}
static __device__ __forceinline__ void l_store(int* L, int i, int v) {
    __hip_atomic_store(&L[i], v, __ATOMIC_RELAXED, __HIP_MEMORY_SCOPE_WORKGROUP);
}
static __device__ int l_find(int* L, int i) {
    while (true) {
        const int p = l_load(L, i);
        if (p == i) return i;
        const int gp = l_load(L, p);
        if (gp == p) return p;
        l_store(L, i, gp);
        i = gp;
    }
}
static __device__ void l_unite(int* L, int a, int b) {
    while (true) {
        a = l_find(L, a); b = l_find(L, b);
        if (a == b) return;
        const int lo = a < b ? a : b;
        const int hi = a ^ b ^ lo;
        const int old = atomicMin(&L[hi], lo);
        if (old == hi) return;
        a = lo; b = old;
    }
}

// ======= fused pass A+B: mask + tanh + run-based tile CCL (4 barriers) ======
__global__ __launch_bounds__(256) void k_tile(const float* __restrict__ x,
                                              int* __restrict__ G,
                                              int* __restrict__ topM, int* __restrict__ botM,
                                              int* __restrict__ leftM, int* __restrict__ rightM,
                                              int* __restrict__ rootsArr,
                                              double* __restrict__ partials) {
    __shared__ u64 mrow[64];
    __shared__ u64 rstart[64];
    __shared__ unsigned int mpart[64][4];
    __shared__ int rowbase[64];
    __shared__ int P[SLOTS];
    __shared__ int wtot[4];
    __shared__ double wsum[4];
    __shared__ int Rtot;
    const int t = threadIdx.x;
    const int tile = blockIdx.x;
    const int tr = tile >> 6, tc = tile & 63;

    // --- ph1: load own 16 pixels (row r, quarter qd): mask + tanh sum ---
    const int r = t >> 2, qd = t & 3;
    const float4* xp = reinterpret_cast<const float4*>(
        x + ((size_t)((tr << 6) | r) << 12) + (tc << 6) + (qd << 4));
    unsigned int m16 = 0;
    float sf = 0.0f;
    #pragma unroll
    for (int k = 0; k < 4; ++k) {
        const float4 a = xp[k];
        const float vv[4] = {a.x, a.y, a.z, a.w};
        #pragma unroll
        for (int j = 0; j < 4; ++j) {
            const float v = vv[j];
            if (v > 0.0f) {                        // tanh(x)>0 <=> x>0
                m16 |= 1u << (k * 4 + j);
                const float e = __expf(2.0f * v);  // tanh = 1 - 2/(e^{2x}+1)
                sf += 1.0f - 2.0f * __builtin_amdgcn_rcpf(e + 1.0f);
            }
        }
    }
    mpart[r][qd] = m16;
    double s = (double)sf;
    for (int off = 32; off > 0; off >>= 1) s += __shfl_down(s, off, 64);
    if ((t & 63) == 0) wsum[t >> 6] = s;
    __syncthreads();                                             // b1

    // --- ph2: wave0 row masks + run scan; all: P init ---
    if (t < 64) {
        const u64 m = (u64)mpart[t][0] | ((u64)mpart[t][1] << 16)
                    | ((u64)mpart[t][2] << 32) | ((u64)mpart[t][3] << 48);
        mrow[t] = m;
        const u64 rs = m & ~(m << 1);
        rstart[t] = rs;
        int inc = __popcll(rs);
        const int nr = inc;
        #pragma unroll
        for (int off = 1; off < 64; off <<= 1) {
            const int v = __shfl_up(inc, off, 64);
            if (t >= off) inc += v;
        }
        rowbase[t] = inc - nr;
        if (t == 63) Rtot = inc;
    }
    #pragma unroll
    for (int i = t; i < SLOTS; i += 256) P[i] = i;
    if (t == 0) partials[tile] = wsum[0] + wsum[1] + wsum[2] + wsum[3];
    __syncthreads();                                             // b2

    // --- ph3: unions, one per overlap segment (hook fast-path) ---
    {
        const int rr = t >> 2;
        if (rr >= 1) {
            const u64 vm = mrow[rr] & mrow[rr - 1];
            u64 st = vm & ~(vm << 1);
            const int cb = (t & 3) * 16;
            st = (st >> cb) & 0xFFFFull;
            if (st) {
                const u64 rs  = rstart[rr];
                const u64 rsu = rstart[rr - 1];
                const int rb  = rowbase[rr];
                const int rbu = rowbase[rr - 1];
                do {
                    const int j = __builtin_ctzll(st) + cb;
                    const u64 thru = ~0ull >> (63 - j);
                    const int na = rb  + __popcll(rs  & thru) - 1;
                    const int nb = rbu + __popcll(rsu & thru) - 1;
                    const int old = atomicMin(&P[na], nb);
                    if (old != na && old != nb) l_unite(P, nb, old);
                    st &= st - 1;
                } while (st);
            }
        }
    }
    __syncthreads();                                             // b3

    // --- ph4: border finds -> publish LOCAL ROOT ids; count roots; G init ---
    const int R = Rtot;
    const int tileBase = tile * SLOTS;
    {
        int rr, j;
        if (t < 64)       { rr = 0;       j = t; }
        else if (t < 128) { rr = 63;      j = t - 64; }
        else if (t < 192) { rr = t - 128; j = 0; }
        else              { rr = t - 192; j = 63; }
        int node = -1;
        if ((mrow[rr] >> j) & 1ull) {
            const int idx = __popcll(rstart[rr] & (~0ull >> (63 - j))) - 1;
            node = tileBase + l_find(P, rowbase[rr] + idx);   // true root (post-b3)
        }
        const int bi = (tile << 6) | (t & 63);
        if (t < 64)       topM[bi]   = node;
        else if (t < 128) botM[bi]   = node;
        else if (t < 192) leftM[bi]  = node;
        else              rightM[bi] = node;
    }
    int c = 0;
    #pragma unroll 4
    for (int i = t; i < R; i += 256) c += (P[i] == i);  // halving never flips root status
    for (int off = 32; off > 0; off >>= 1) c += __shfl_down(c, off, 64);
    if ((t & 63) == 0) wtot[t >> 6] = c;
    // identity G init over all runs (root slots are the only entry points)
    for (int i = t; i < R; i += 256) G[tileBase + i] = tileBase + i;
    __syncthreads();                                             // b4
    if (t == 0) rootsArr[tile] = wtot[0] + wtot[1] + wtot[2] + wtot[3];
}

// ================= pass C: cross-tile unions (per-tile link counts) =========
__global__ __launch_bounds__(128) void k_xmerge(const int* __restrict__ topM,
                                                const int* __restrict__ botM,
                                                const int* __restrict__ leftM,
                                                const int* __restrict__ rightM,
                                                int* G, int* __restrict__ linksArr) {
    __shared__ int lsum[2];
    const int t = threadIdx.x, tile = blockIdx.x;
    const int tr = tile >> 6, tc = tile & 63;
    int links = 0;
    if (t < 64) {
        if (tr > 0) {
            const int a = topM[(tile << 6) | t];
            const int b = botM[((tile - 64) << 6) | t];
            const int ap = __shfl_up(a, 1, 64);
            const int bp = __shfl_up(b, 1, 64);
            if ((a | b) >= 0) {                    // both masked
                const bool redund = (t > 0) && ((ap | bp) >= 0);
                if (!redund) links = g_unite(G, a, b);
            }
        }
    } else {
        const int rr = t - 64;
        if (tc > 0) {
            const int a = leftM[(tile << 6) | rr];
            const int b = rightM[((tile - 1) << 6) | rr];
            const int ap = __shfl_up(a, 1, 64);
            const int bp = __shfl_up(b, 1, 64);
            if ((a | b) >= 0) {
                const bool redund = (rr > 0) && ((ap | bp) >= 0);
                if (!redund) links = g_unite(G, a, b);
            }
        }
    }
    for (int off = 32; off > 0; off >>= 1) links += __shfl_down(links, off, 64);
    if ((t & 63) == 0) lsum[t >> 6] = links;
    __syncthreads();
    if (t == 0) linksArr[tile] = lsum[0] + lsum[1];
}

// ================= pass D: tiny final reduction =================
__global__ __launch_bounds__(256) void k_final(const double* __restrict__ partials,
                                               const int* __restrict__ rootsArr,
                                               const int* __restrict__ linksArr,
                                               float* __restrict__ out) {
    __shared__ double sd[256];
    __shared__ int si[256];
    const int t = threadIdx.x;
    double s = 0.0; int n = 0;
    for (int i = t; i < NTILES; i += 256) {
        s += partials[i];
        n += rootsArr[i] - linksArr[i];
    }
    sd[t] = s; si[t] = n; __syncthreads();
    for (int off = 128; off > 0; off >>= 1) {
        if (t < off) { sd[t] += sd[t + off]; si[t] += si[t + off]; }
        __syncthreads();
    }
    if (t == 0) {
        const int nn = si[0];
        // sum_c S_c/(N+1-c) ~= (sum S)/(N+1): rel err ~ <c>/N ~ 2e-6 << 2e-2 tol
        out[0] = (nn > 0) ? (float)(sd[0] / (double)(NPIX + 1) / (double)nn) : 0.0f;
    }
}

// ================= launch =================
extern "C" void kernel_launch(void* const* d_in, const int* in_sizes, int n_in,
                              void* d_out, int out_size, void* d_ws, size_t ws_size,
                              hipStream_t stream) {
    const float* x = (const float*)d_in[0];
    float* out = (float*)d_out;

    char* ws = (char*)d_ws;
    int* G = (int*)ws;                                         // 32 MB
    int* topM   = (int*)(ws + (32u << 20));                    // 1 MB each
    int* botM   = topM  + NTILES * 64;
    int* leftM  = botM  + NTILES * 64;
    int* rightM = leftM + NTILES * 64;
    double* partials = (double*)(ws + (36u << 20));            // 32 KB
    int* rootsArr = (int*)(ws + (36u << 20) + (64u << 10));    // 16 KB
    int* linksArr = (int*)(ws + (36u << 20) + (80u << 10));    // 16 KB

    k_tile  <<<NTILES, 256, 0, stream>>>(x, G, topM, botM, leftM, rightM,
                                         rootsArr, partials);
    k_xmerge<<<NTILES, 128, 0, stream>>>(topM, botM, leftM, rightM, G, linksArr);
    k_final <<<1, 256, 0, stream>>>(partials, rootsArr, linksArr, out);
}